// Round 1
// baseline (487.054 us; speedup 1.0000x reference)
//
#include <hip/hip_runtime.h>
#include <math.h>

#define BB 4
#define RR 8192
#define SS 32
#define IN_DIM 180
#define SLOT_DIM 1536
#define ATT 1536

// ---------------------------------------------------------------------------
// K1: k_ws[b][s][a] = sum_i slot[b][s][i] * Wk[i][a]
// grid (32 s-blocks, 6 a-tiles of 256), block 256.
// slot rows (all 4 batches for this s) staged in LDS; Wk reads coalesced.
// ---------------------------------------------------------------------------
__global__ __launch_bounds__(256) void k_proj_kernel(const float* __restrict__ slot,
                                                     const float* __restrict__ Wk,
                                                     float* __restrict__ k_ws) {
    __shared__ __align__(16) float sl[BB * SLOT_DIM];  // 24 KB
    const int s  = blockIdx.x;
    const int a0 = blockIdx.y * 256;
    const int t  = threadIdx.x;

    for (int idx = t; idx < BB * SLOT_DIM; idx += 256) {
        int b = idx / SLOT_DIM, i = idx - b * SLOT_DIM;
        sl[idx] = slot[((size_t)(b * SS + s)) * SLOT_DIM + i];
    }
    __syncthreads();

    float acc0 = 0.f, acc1 = 0.f, acc2 = 0.f, acc3 = 0.f;
    const int a = a0 + t;
    const float* wkp = Wk + a;
#pragma unroll 8
    for (int i = 0; i < SLOT_DIM; ++i) {
        float wk = wkp[(size_t)i * ATT];
        acc0 += sl[0 * SLOT_DIM + i] * wk;
        acc1 += sl[1 * SLOT_DIM + i] * wk;
        acc2 += sl[2 * SLOT_DIM + i] * wk;
        acc3 += sl[3 * SLOT_DIM + i] * wk;
    }
    k_ws[((size_t)(0 * SS + s)) * ATT + a] = acc0;
    k_ws[((size_t)(1 * SS + s)) * ATT + a] = acc1;
    k_ws[((size_t)(2 * SS + s)) * ATT + a] = acc2;
    k_ws[((size_t)(3 * SS + s)) * ATT + a] = acc3;
}

// ---------------------------------------------------------------------------
// K2: M_ws[b][i][s] = scale * sum_a Wq[i][a] * k_ws[b][s][a]
// grid (B*S = 128), block 256 = 4 waves. One wave per output i, lanes split a,
// shfl-xor reduce over 64 lanes. Wq row reads are 64-lane contiguous.
// ---------------------------------------------------------------------------
__global__ __launch_bounds__(256) void m_kernel(const float* __restrict__ Wq,
                                                const float* __restrict__ k_ws,
                                                float* __restrict__ M_ws) {
    __shared__ __align__(16) float kr[ATT];  // 6 KB
    const int bs = blockIdx.x;
    const int b = bs / SS, s = bs - b * SS;
    const int t = threadIdx.x;

    for (int idx = t; idx < ATT; idx += 256) kr[idx] = k_ws[(size_t)bs * ATT + idx];
    __syncthreads();

    const int wave = t >> 6, lane = t & 63;
    const float scale = 0.0255155181f;  // 1536^-0.5

    for (int i = wave; i < IN_DIM; i += 4) {
        const float* wq = Wq + (size_t)i * ATT;
        float p = 0.f;
#pragma unroll 4
        for (int a = lane; a < ATT; a += 64) p += wq[a] * kr[a];
        // full-wave butterfly reduce
        for (int m = 32; m >= 1; m >>= 1) p += __shfl_xor(p, m, 64);
        if (lane == 0) M_ws[((size_t)b * IN_DIM + i) * SS + s] = p * scale;
    }
}

// ---------------------------------------------------------------------------
// K3: dots = x @ M  -> softmax over s -> write w output.
// grid (R/32 tiles, B), block 256. x tile + M in LDS.
// thread t computes 4 dots: row r = t>>3, slots 4*(t&7)..+3.
// ---------------------------------------------------------------------------
__global__ __launch_bounds__(256) void attn_w_kernel(const float* __restrict__ x,
                                                     const float* __restrict__ M_ws,
                                                     float* __restrict__ w_out) {
    const int TR = 32;
    __shared__ __align__(16) float xs[TR * IN_DIM];   // 23 KB
    __shared__ __align__(16) float Ms[IN_DIM * SS];   // 23 KB
    __shared__ __align__(16) float wt[TR * 33];       // padded, 4.2 KB
    const int b  = blockIdx.y;
    const int r0 = blockIdx.x * TR;
    const int t  = threadIdx.x;

    // x tile: contiguous TR*180 floats
    {
        const float4* src = (const float4*)(x + ((size_t)b * RR + r0) * IN_DIM);
        float4* dst = (float4*)xs;
        for (int idx = t; idx < TR * IN_DIM / 4; idx += 256) dst[idx] = src[idx];
    }
    {
        const float4* src = (const float4*)(M_ws + (size_t)b * IN_DIM * SS);
        float4* dst = (float4*)Ms;
        for (int idx = t; idx < IN_DIM * SS / 4; idx += 256) dst[idx] = src[idx];
    }
    __syncthreads();

    const int r = t >> 3, sq = (t & 7) * 4;
    float a0 = 0.f, a1 = 0.f, a2 = 0.f, a3 = 0.f;
#pragma unroll 4
    for (int i = 0; i < IN_DIM; ++i) {
        float xv = xs[r * IN_DIM + i];
        const float4 m4 = *(const float4*)(Ms + i * SS + sq);
        a0 += xv * m4.x; a1 += xv * m4.y; a2 += xv * m4.z; a3 += xv * m4.w;
    }
    wt[r * 33 + sq + 0] = a0;
    wt[r * 33 + sq + 1] = a1;
    wt[r * 33 + sq + 2] = a2;
    wt[r * 33 + sq + 3] = a3;
    __syncthreads();

    if (t < TR) {
        float mx = -1e30f;
#pragma unroll
        for (int j = 0; j < SS; ++j) mx = fmaxf(mx, wt[t * 33 + j]);
        float sum = 0.f;
#pragma unroll
        for (int j = 0; j < SS; ++j) {
            float e = __expf(wt[t * 33 + j] - mx);
            wt[t * 33 + j] = e;
            sum += e;
        }
        float inv = 1.0f / sum;
#pragma unroll
        for (int j = 0; j < SS; ++j) wt[t * 33 + j] *= inv;
    }
    __syncthreads();

    float* wg = w_out + ((size_t)b * RR + r0) * SS;
    for (int idx = t; idx < TR * SS; idx += 256) {
        int rr = idx >> 5, ss = idx & 31;
        wg[idx] = wt[rr * 33 + ss];
    }
}

// ---------------------------------------------------------------------------
// K4: s_out[b][r][d] = sum_s w[b][r][s] * slot[b][s][d]
// grid (R/64, 1536/256, B), block 256. Tiles: 64 rows x 256 d.
// thread: dq = t&63 -> 4 consecutive d; rg = t>>6 -> 16 rows. acc[16] float4.
// ---------------------------------------------------------------------------
__global__ __launch_bounds__(256) void out_kernel(const float* __restrict__ slot,
                                                  const float* __restrict__ w_g,
                                                  float* __restrict__ out) {
    const int TRO = 64, TD = 256;
    __shared__ __align__(16) float wt[TRO * SS];  // 8 KB
    __shared__ __align__(16) float st[SS * TD];   // 32 KB
    const int b  = blockIdx.z;
    const int r0 = blockIdx.x * TRO;
    const int d0 = blockIdx.y * TD;
    const int t  = threadIdx.x;

    {
        const float4* src = (const float4*)(w_g + ((size_t)b * RR + r0) * SS);
        float4* dst = (float4*)wt;
        for (int idx = t; idx < TRO * SS / 4; idx += 256) dst[idx] = src[idx];
    }
#pragma unroll 4
    for (int ss = 0; ss < SS; ++ss) {
        st[ss * TD + t] = slot[((size_t)b * SS + ss) * SLOT_DIM + d0 + t];
    }
    __syncthreads();

    const int dq = (t & 63) * 4, rg = (t >> 6) * 16;
    float4 acc[16];
#pragma unroll
    for (int r = 0; r < 16; ++r) acc[r] = make_float4(0.f, 0.f, 0.f, 0.f);

    for (int ss = 0; ss < SS; ++ss) {
        const float4 v = *(const float4*)(st + ss * TD + dq);
#pragma unroll
        for (int r = 0; r < 16; ++r) {
            float wv = wt[(rg + r) * SS + ss];
            acc[r].x += wv * v.x;
            acc[r].y += wv * v.y;
            acc[r].z += wv * v.z;
            acc[r].w += wv * v.w;
        }
    }

#pragma unroll
    for (int r = 0; r < 16; ++r) {
        *(float4*)(out + ((size_t)b * RR + r0 + rg + r) * SLOT_DIM + d0 + dq) = acc[r];
    }
}

// ---------------------------------------------------------------------------
extern "C" void kernel_launch(void* const* d_in, const int* in_sizes, int n_in,
                              void* d_out, int out_size, void* d_ws, size_t ws_size,
                              hipStream_t stream) {
    const float* x    = (const float*)d_in[0];  // [4, 8192, 180]
    const float* slot = (const float*)d_in[1];  // [4, 32, 1536]
    const float* Wq   = (const float*)d_in[2];  // [180, 1536]
    const float* Wk   = (const float*)d_in[3];  // [1536, 1536]

    float* out   = (float*)d_out;                        // s: [4, 8192, 1536]
    float* w_out = out + (size_t)BB * RR * SLOT_DIM;     // w: [4, 8192, 32]

    float* k_ws = (float*)d_ws;                          // [4, 32, 1536] = 786 KB
    float* M_ws = k_ws + (size_t)BB * SS * ATT;          // [4, 180, 32]  = 92 KB

    k_proj_kernel<<<dim3(SS, ATT / 256), 256, 0, stream>>>(slot, Wk, k_ws);
    m_kernel<<<dim3(BB * SS), 256, 0, stream>>>(Wq, k_ws, M_ws);
    attn_w_kernel<<<dim3(RR / 32, BB), 256, 0, stream>>>(x, M_ws, w_out);
    out_kernel<<<dim3(RR / 64, SLOT_DIM / 256, BB), 256, 0, stream>>>(slot, w_out, out);
}

// Round 2
// 304.261 us; speedup vs baseline: 1.6008x; 1.6008x over previous
//
#include <hip/hip_runtime.h>
#include <math.h>

#define BB 4
#define RR 8192
#define SS 32
#define IN_DIM 180
#define SLOT_DIM 1536
#define ATT 1536

// ---------------------------------------------------------------------------
// K1: k_ws[b][s][a] += sum_{i in chunk} slot[b][s][i] * Wk[i][a]
// grid (32 s, 6 a-tiles of 256, 4 i-chunks of 384), block 256.
// k_ws must be zeroed before launch (atomic accumulation over i-chunks).
// ---------------------------------------------------------------------------
__global__ __launch_bounds__(256) void k_proj_kernel(const float* __restrict__ slot,
                                                     const float* __restrict__ Wk,
                                                     float* __restrict__ k_ws) {
    const int ICH = 384;
    __shared__ __align__(16) float sl[BB * ICH];  // 6 KB
    const int s  = blockIdx.x;
    const int a0 = blockIdx.y * 256;
    const int i0 = blockIdx.z * ICH;
    const int t  = threadIdx.x;

    for (int idx = t; idx < BB * ICH; idx += 256) {
        int b = idx / ICH, ii = idx - b * ICH;
        sl[idx] = slot[((size_t)(b * SS + s)) * SLOT_DIM + i0 + ii];
    }
    __syncthreads();

    float acc0 = 0.f, acc1 = 0.f, acc2 = 0.f, acc3 = 0.f;
    const int a = a0 + t;
    const float* wkp = Wk + (size_t)i0 * ATT + a;
#pragma unroll 8
    for (int ii = 0; ii < ICH; ++ii) {
        float wk = wkp[(size_t)ii * ATT];
        acc0 += sl[0 * ICH + ii] * wk;
        acc1 += sl[1 * ICH + ii] * wk;
        acc2 += sl[2 * ICH + ii] * wk;
        acc3 += sl[3 * ICH + ii] * wk;
    }
    atomicAdd(&k_ws[((size_t)(0 * SS + s)) * ATT + a], acc0);
    atomicAdd(&k_ws[((size_t)(1 * SS + s)) * ATT + a], acc1);
    atomicAdd(&k_ws[((size_t)(2 * SS + s)) * ATT + a], acc2);
    atomicAdd(&k_ws[((size_t)(3 * SS + s)) * ATT + a], acc3);
}

// ---------------------------------------------------------------------------
// K2: M_ws[b][i][s] = scale * sum_a Wq[i][a] * k_ws[b][s][a]
// grid (B*S = 128, 45 i-groups), block 256 = 4 waves. One wave per (i, bs).
// Lanes split the 1536-length dot; butterfly reduce; lane 0 stores.
// ---------------------------------------------------------------------------
__global__ __launch_bounds__(256) void m_kernel(const float* __restrict__ Wq,
                                                const float* __restrict__ k_ws,
                                                float* __restrict__ M_ws) {
    __shared__ __align__(16) float kr[ATT];  // 6 KB
    const int bs = blockIdx.x;
    const int b = bs / SS, s = bs - b * SS;
    const int t = threadIdx.x;

    for (int idx = t; idx < ATT; idx += 256) kr[idx] = k_ws[(size_t)bs * ATT + idx];
    __syncthreads();

    const int wave = t >> 6, lane = t & 63;
    const int i = blockIdx.y * 4 + wave;  // 45*4 = 180, always in range
    const float scale = 0.0255155181f;    // 1536^-0.5

    const float* wq = Wq + (size_t)i * ATT;
    float p = 0.f;
#pragma unroll
    for (int j = 0; j < ATT / 64; ++j) {
        int a = lane + j * 64;
        p += wq[a] * kr[a];
    }
    for (int m = 32; m >= 1; m >>= 1) p += __shfl_xor(p, m, 64);
    if (lane == 0) M_ws[((size_t)b * IN_DIM + i) * SS + s] = p * scale;
}

// ---------------------------------------------------------------------------
// K3: dots = x @ M  -> softmax over s -> write w output.
// grid (R/32 tiles, B), block 256. x tile + M in LDS.
// thread t computes 4 dots: row r = t>>3, slots 4*(t&7)..+3.
// ---------------------------------------------------------------------------
__global__ __launch_bounds__(256) void attn_w_kernel(const float* __restrict__ x,
                                                     const float* __restrict__ M_ws,
                                                     float* __restrict__ w_out) {
    const int TR = 32;
    __shared__ __align__(16) float xs[TR * IN_DIM];   // 23 KB
    __shared__ __align__(16) float Ms[IN_DIM * SS];   // 23 KB
    __shared__ __align__(16) float wt[TR * 33];       // padded, 4.2 KB
    const int b  = blockIdx.y;
    const int r0 = blockIdx.x * TR;
    const int t  = threadIdx.x;

    {
        const float4* src = (const float4*)(x + ((size_t)b * RR + r0) * IN_DIM);
        float4* dst = (float4*)xs;
        for (int idx = t; idx < TR * IN_DIM / 4; idx += 256) dst[idx] = src[idx];
    }
    {
        const float4* src = (const float4*)(M_ws + (size_t)b * IN_DIM * SS);
        float4* dst = (float4*)Ms;
        for (int idx = t; idx < IN_DIM * SS / 4; idx += 256) dst[idx] = src[idx];
    }
    __syncthreads();

    const int r = t >> 3, sq = (t & 7) * 4;
    float a0 = 0.f, a1 = 0.f, a2 = 0.f, a3 = 0.f;
#pragma unroll 4
    for (int i = 0; i < IN_DIM; ++i) {
        float xv = xs[r * IN_DIM + i];
        const float4 m4 = *(const float4*)(Ms + i * SS + sq);
        a0 += xv * m4.x; a1 += xv * m4.y; a2 += xv * m4.z; a3 += xv * m4.w;
    }
    wt[r * 33 + sq + 0] = a0;
    wt[r * 33 + sq + 1] = a1;
    wt[r * 33 + sq + 2] = a2;
    wt[r * 33 + sq + 3] = a3;
    __syncthreads();

    if (t < TR) {
        float mx = -1e30f;
#pragma unroll
        for (int j = 0; j < SS; ++j) mx = fmaxf(mx, wt[t * 33 + j]);
        float sum = 0.f;
#pragma unroll
        for (int j = 0; j < SS; ++j) {
            float e = __expf(wt[t * 33 + j] - mx);
            wt[t * 33 + j] = e;
            sum += e;
        }
        float inv = 1.0f / sum;
#pragma unroll
        for (int j = 0; j < SS; ++j) wt[t * 33 + j] *= inv;
    }
    __syncthreads();

    float* wg = w_out + ((size_t)b * RR + r0) * SS;
    for (int idx = t; idx < TR * SS; idx += 256) {
        int rr = idx >> 5, ss = idx & 31;
        wg[idx] = wt[rr * 33 + ss];
    }
}

// ---------------------------------------------------------------------------
// K4: s_out[b][r][d] = sum_s w[b][r][s] * slot[b][s][d]
// grid (R/64, 1536/256, B), block 256. Tiles: 64 rows x 256 d.
// thread: dq = t&63 -> 4 consecutive d; rg = t>>6 -> 16 rows. acc[16] float4.
// ---------------------------------------------------------------------------
__global__ __launch_bounds__(256) void out_kernel(const float* __restrict__ slot,
                                                  const float* __restrict__ w_g,
                                                  float* __restrict__ out) {
    const int TRO = 64, TD = 256;
    __shared__ __align__(16) float wt[TRO * SS];  // 8 KB
    __shared__ __align__(16) float st[SS * TD];   // 32 KB
    const int b  = blockIdx.z;
    const int r0 = blockIdx.x * TRO;
    const int d0 = blockIdx.y * TD;
    const int t  = threadIdx.x;

    {
        const float4* src = (const float4*)(w_g + ((size_t)b * RR + r0) * SS);
        float4* dst = (float4*)wt;
        for (int idx = t; idx < TRO * SS / 4; idx += 256) dst[idx] = src[idx];
    }
#pragma unroll 4
    for (int ss = 0; ss < SS; ++ss) {
        st[ss * TD + t] = slot[((size_t)b * SS + ss) * SLOT_DIM + d0 + t];
    }
    __syncthreads();

    const int dq = (t & 63) * 4, rg = (t >> 6) * 16;
    float4 acc[16];
#pragma unroll
    for (int r = 0; r < 16; ++r) acc[r] = make_float4(0.f, 0.f, 0.f, 0.f);

    for (int ss = 0; ss < SS; ++ss) {
        const float4 v = *(const float4*)(st + ss * TD + dq);
#pragma unroll
        for (int r = 0; r < 16; ++r) {
            float wv = wt[(rg + r) * SS + ss];
            acc[r].x += wv * v.x;
            acc[r].y += wv * v.y;
            acc[r].z += wv * v.z;
            acc[r].w += wv * v.w;
        }
    }

#pragma unroll
    for (int r = 0; r < 16; ++r) {
        *(float4*)(out + ((size_t)b * RR + r0 + rg + r) * SLOT_DIM + d0 + dq) = acc[r];
    }
}

// ---------------------------------------------------------------------------
extern "C" void kernel_launch(void* const* d_in, const int* in_sizes, int n_in,
                              void* d_out, int out_size, void* d_ws, size_t ws_size,
                              hipStream_t stream) {
    const float* x    = (const float*)d_in[0];  // [4, 8192, 180]
    const float* slot = (const float*)d_in[1];  // [4, 32, 1536]
    const float* Wq   = (const float*)d_in[2];  // [180, 1536]
    const float* Wk   = (const float*)d_in[3];  // [1536, 1536]

    float* out   = (float*)d_out;                        // s: [4, 8192, 1536]
    float* w_out = out + (size_t)BB * RR * SLOT_DIM;     // w: [4, 8192, 32]

    float* k_ws = (float*)d_ws;                          // [4, 32, 1536] = 786 KB
    float* M_ws = k_ws + (size_t)BB * SS * ATT;          // [4, 180, 32]  = 92 KB

    // k_ws is accumulated with atomics -> zero it (ws is poisoned 0xAA).
    hipMemsetAsync(k_ws, 0, (size_t)BB * SS * ATT * sizeof(float), stream);

    k_proj_kernel<<<dim3(SS, ATT / 256, SLOT_DIM / 384), 256, 0, stream>>>(slot, Wk, k_ws);
    m_kernel<<<dim3(BB * SS, IN_DIM / 4), 256, 0, stream>>>(Wq, k_ws, M_ws);
    attn_w_kernel<<<dim3(RR / 32, BB), 256, 0, stream>>>(x, M_ws, w_out);
    out_kernel<<<dim3(RR / 64, SLOT_DIM / 256, BB), 256, 0, stream>>>(slot, w_out, out);
}

// Round 4
// 300.772 us; speedup vs baseline: 1.6193x; 1.0116x over previous
//
#include <hip/hip_runtime.h>
#include <math.h>

#define BB 4
#define RR 8192
#define SS 32
#define IN_DIM 180
#define SLOT_DIM 1536
#define ATT 1536

// ---------------------------------------------------------------------------
// K1: k_ws[b][s][a] += sum_{i in chunk} slot[b][s][i] * Wk[i][a]
// grid (32 s, 6 a-tiles of 256, 8 i-chunks of 192), block 256.
// sl staged TRANSPOSED: sl[ii][b] -> one broadcast b128 read per iter.
// k_ws must be zeroed before launch (atomic accumulation over i-chunks).
// ---------------------------------------------------------------------------
__global__ __launch_bounds__(256) void k_proj_kernel(const float* __restrict__ slot,
                                                     const float* __restrict__ Wk,
                                                     float* __restrict__ k_ws) {
    const int ICH = 192;
    __shared__ __align__(16) float sl[ICH * BB];  // 3 KB, [ii][b]
    const int s  = blockIdx.x;
    const int a0 = blockIdx.y * 256;
    const int i0 = blockIdx.z * ICH;
    const int t  = threadIdx.x;

    for (int idx = t; idx < BB * ICH; idx += 256) {
        int b = idx / ICH, ii = idx - b * ICH;
        sl[ii * BB + b] = slot[((size_t)(b * SS + s)) * SLOT_DIM + i0 + ii];
    }
    __syncthreads();

    float acc0 = 0.f, acc1 = 0.f, acc2 = 0.f, acc3 = 0.f;
    const int a = a0 + t;
    const float* wkp = Wk + (size_t)i0 * ATT + a;
#pragma unroll 8
    for (int ii = 0; ii < ICH; ++ii) {
        float wk = wkp[(size_t)ii * ATT];
        const float4 s4 = *(const float4*)(sl + ii * BB);
        acc0 += s4.x * wk;
        acc1 += s4.y * wk;
        acc2 += s4.z * wk;
        acc3 += s4.w * wk;
    }
    atomicAdd(&k_ws[((size_t)(0 * SS + s)) * ATT + a], acc0);
    atomicAdd(&k_ws[((size_t)(1 * SS + s)) * ATT + a], acc1);
    atomicAdd(&k_ws[((size_t)(2 * SS + s)) * ATT + a], acc2);
    atomicAdd(&k_ws[((size_t)(3 * SS + s)) * ATT + a], acc3);
}

// ---------------------------------------------------------------------------
// K2: M_ws[b][i][s] = scale * sum_a Wq[i][a] * k_ws[b][s][a]
// grid (B*S = 128, 45 i-groups), block 256 = 4 waves. One wave per (i, bs).
// ---------------------------------------------------------------------------
__global__ __launch_bounds__(256) void m_kernel(const float* __restrict__ Wq,
                                                const float* __restrict__ k_ws,
                                                float* __restrict__ M_ws) {
    __shared__ __align__(16) float kr[ATT];  // 6 KB
    const int bs = blockIdx.x;
    const int b = bs / SS, s = bs - b * SS;
    const int t = threadIdx.x;

    for (int idx = t; idx < ATT; idx += 256) kr[idx] = k_ws[(size_t)bs * ATT + idx];
    __syncthreads();

    const int wave = t >> 6, lane = t & 63;
    const int i = blockIdx.y * 4 + wave;  // 45*4 = 180
    const float scale = 0.0255155181f;    // 1536^-0.5

    const float* wq = Wq + (size_t)i * ATT;
    float p = 0.f;
#pragma unroll
    for (int j = 0; j < ATT / 64; ++j) {
        int a = lane + j * 64;
        p += wq[a] * kr[a];
    }
    for (int m = 32; m >= 1; m >>= 1) p += __shfl_xor(p, m, 64);
    if (lane == 0) M_ws[((size_t)b * IN_DIM + i) * SS + s] = p * scale;
}

// ---------------------------------------------------------------------------
// K3: dots = x @ M  -> softmax over s -> write w output.
// grid (R/64, B), block 256. TR=64 rows/tile, 2 rows x 4 slots per thread.
// M read directly from global (23 KB, L1/L2-resident, coalesced float4) to
// keep LDS = 54.5 KB < 64 KB per-workgroup limit.
// ---------------------------------------------------------------------------
__global__ __launch_bounds__(256) void attn_w_kernel(const float* __restrict__ x,
                                                     const float* __restrict__ M_ws,
                                                     float* __restrict__ w_out) {
    const int TR = 64;
    __shared__ __align__(16) float xs[TR * IN_DIM];   // 46 KB
    __shared__ __align__(16) float wt[TR * 33];       // padded, 8.4 KB
    const int b  = blockIdx.y;
    const int r0 = blockIdx.x * TR;
    const int t  = threadIdx.x;

    {
        const float4* src = (const float4*)(x + ((size_t)b * RR + r0) * IN_DIM);
        float4* dst = (float4*)xs;
        for (int idx = t; idx < TR * IN_DIM / 4; idx += 256) dst[idx] = src[idx];
    }
    __syncthreads();

    const float* Mg = M_ws + (size_t)b * IN_DIM * SS;
    const int rp = t >> 3;             // 0..31 -> rows 2*rp, 2*rp+1
    const int sq = (t & 7) * 4;
    const int ra = rp * 2, rb = ra + 1;
    float4 A = make_float4(0.f, 0.f, 0.f, 0.f);
    float4 Bv = make_float4(0.f, 0.f, 0.f, 0.f);
#pragma unroll 4
    for (int i = 0; i < IN_DIM; ++i) {
        float x0 = xs[ra * IN_DIM + i];
        float x1 = xs[rb * IN_DIM + i];
        const float4 m4 = *(const float4*)(Mg + i * SS + sq);
        A.x += x0 * m4.x; A.y += x0 * m4.y; A.z += x0 * m4.z; A.w += x0 * m4.w;
        Bv.x += x1 * m4.x; Bv.y += x1 * m4.y; Bv.z += x1 * m4.z; Bv.w += x1 * m4.w;
    }
    wt[ra * 33 + sq + 0] = A.x;  wt[ra * 33 + sq + 1] = A.y;
    wt[ra * 33 + sq + 2] = A.z;  wt[ra * 33 + sq + 3] = A.w;
    wt[rb * 33 + sq + 0] = Bv.x; wt[rb * 33 + sq + 1] = Bv.y;
    wt[rb * 33 + sq + 2] = Bv.z; wt[rb * 33 + sq + 3] = Bv.w;
    __syncthreads();

    if (t < TR) {
        float mx = -1e30f;
#pragma unroll
        for (int j = 0; j < SS; ++j) mx = fmaxf(mx, wt[t * 33 + j]);
        float sum = 0.f;
#pragma unroll
        for (int j = 0; j < SS; ++j) {
            float e = __expf(wt[t * 33 + j] - mx);
            wt[t * 33 + j] = e;
            sum += e;
        }
        float inv = 1.0f / sum;
#pragma unroll
        for (int j = 0; j < SS; ++j) wt[t * 33 + j] *= inv;
    }
    __syncthreads();

    float* wg = w_out + ((size_t)b * RR + r0) * SS;
    for (int idx = t; idx < TR * SS; idx += 256) {
        int rr = idx >> 5, ss = idx & 31;
        wg[idx] = wt[rr * 33 + ss];
    }
}

// ---------------------------------------------------------------------------
// K4: s_out[b][r][d] = sum_s w[b][r][s] * slot[b][s][d]
// grid (R/64, 1536/256, B), block 256. Tile 64r x 256d; thread = 8r x 8d.
// w staged TRANSPOSED in LDS (wtT[ss][r], pad 68) -> 8 row-weights per
// 2 b128 reads. Slot tile staged as 2048 float4 (k<8 — R3's bug was k<2).
// ---------------------------------------------------------------------------
__global__ __launch_bounds__(256) void out_kernel(const float* __restrict__ slot,
                                                  const float* __restrict__ w_g,
                                                  float* __restrict__ out) {
    const int TRO = 64, TD = 256, WP = 68;
    __shared__ __align__(16) float wtT[SS * WP];  // 8.7 KB, [ss][r] pad 68
    __shared__ __align__(16) float st[SS * TD];   // 32 KB
    const int b  = blockIdx.z;
    const int r0 = blockIdx.x * TRO;
    const int d0 = blockIdx.y * TD;
    const int t  = threadIdx.x;

    // w tile: 64 rows x 32 slots = 512 float4, transpose into wtT
    {
        const float4* src = (const float4*)(w_g + ((size_t)b * RR + r0) * SS);
#pragma unroll
        for (int k = 0; k < 2; ++k) {
            int idx = t + k * 256;                 // 0..511
            int rr = idx >> 3, ssq = (idx & 7) * 4;
            float4 f = src[idx];
            wtT[(ssq + 0) * WP + rr] = f.x;
            wtT[(ssq + 1) * WP + rr] = f.y;
            wtT[(ssq + 2) * WP + rr] = f.z;
            wtT[(ssq + 3) * WP + rr] = f.w;
        }
    }
    // slot tile: 32 rows x 256 cols = 2048 float4
#pragma unroll
    for (int k = 0; k < 8; ++k) {
        int idx = t + k * 256;                     // 0..2047
        int row = idx >> 6, c4 = (idx & 63) * 4;   // row 0..31, c4 0..252
        *(float4*)(st + row * TD + c4) =
            *(const float4*)(slot + ((size_t)(b * SS + row)) * SLOT_DIM + d0 + c4);
    }
    __syncthreads();

    const int d  = (t & 31) * 8;
    const int rg = (t >> 5) * 8;
    float4 acc[8][2];
#pragma unroll
    for (int r = 0; r < 8; ++r) {
        acc[r][0] = make_float4(0.f, 0.f, 0.f, 0.f);
        acc[r][1] = make_float4(0.f, 0.f, 0.f, 0.f);
    }

    for (int ss = 0; ss < SS; ++ss) {
        const float4 v0 = *(const float4*)(st + ss * TD + d);
        const float4 v1 = *(const float4*)(st + ss * TD + d + 4);
        const float4 w0 = *(const float4*)(wtT + ss * WP + rg);
        const float4 w1 = *(const float4*)(wtT + ss * WP + rg + 4);
        const float wr[8] = {w0.x, w0.y, w0.z, w0.w, w1.x, w1.y, w1.z, w1.w};
#pragma unroll
        for (int r = 0; r < 8; ++r) {
            acc[r][0].x += wr[r] * v0.x; acc[r][0].y += wr[r] * v0.y;
            acc[r][0].z += wr[r] * v0.z; acc[r][0].w += wr[r] * v0.w;
            acc[r][1].x += wr[r] * v1.x; acc[r][1].y += wr[r] * v1.y;
            acc[r][1].z += wr[r] * v1.z; acc[r][1].w += wr[r] * v1.w;
        }
    }

#pragma unroll
    for (int r = 0; r < 8; ++r) {
        float* base = out + ((size_t)b * RR + r0 + rg + r) * SLOT_DIM + d0 + d;
        *(float4*)(base + 0) = acc[r][0];
        *(float4*)(base + 4) = acc[r][1];
    }
}

// ---------------------------------------------------------------------------
extern "C" void kernel_launch(void* const* d_in, const int* in_sizes, int n_in,
                              void* d_out, int out_size, void* d_ws, size_t ws_size,
                              hipStream_t stream) {
    const float* x    = (const float*)d_in[0];  // [4, 8192, 180]
    const float* slot = (const float*)d_in[1];  // [4, 32, 1536]
    const float* Wq   = (const float*)d_in[2];  // [180, 1536]
    const float* Wk   = (const float*)d_in[3];  // [1536, 1536]

    float* out   = (float*)d_out;                        // s: [4, 8192, 1536]
    float* w_out = out + (size_t)BB * RR * SLOT_DIM;     // w: [4, 8192, 32]

    float* k_ws = (float*)d_ws;                          // [4, 32, 1536]
    float* M_ws = k_ws + (size_t)BB * SS * ATT;          // [4, 180, 32]

    // k_ws is accumulated with atomics -> zero it (ws is poisoned 0xAA).
    hipMemsetAsync(k_ws, 0, (size_t)BB * SS * ATT * sizeof(float), stream);

    k_proj_kernel<<<dim3(SS, ATT / 256, SLOT_DIM / 192), 256, 0, stream>>>(slot, Wk, k_ws);
    m_kernel<<<dim3(BB * SS, IN_DIM / 4), 256, 0, stream>>>(Wq, k_ws, M_ws);
    attn_w_kernel<<<dim3(RR / 64, BB), 256, 0, stream>>>(x, M_ws, w_out);
    out_kernel<<<dim3(RR / 64, SLOT_DIM / 256, BB), 256, 0, stream>>>(slot, w_out, out);
}